// Round 9
// baseline (143.657 us; speedup 1.0000x reference)
//
#include <hip/hip_runtime.h>
#include <math.h>

// ChamferLoss: target [B,M,2] f32, actual [B,N,2] f32
// out = concat(forward[B,M], backward[B,N]) f32
//
// Round 9: ALGORITHMIC — uniform-grid NN instead of brute force.
// Brute force is at its structural VALU floor (~2.75 lane-ops/pair,
// v_pk_fma_f32 does NOT double fp32 throughput; MFMA numerically dead).
// Grid: per (set=target/actual, b), bucket points into 64x64 cells over
// [-5,5]^2 (N(0,1) data -> ~16 pts/center cell). Query = expanding ring
// search; stop when best_d <= r*cellw (valid for clamped pts: box
// projection is 1-Lipschitz). Every point is in a bucket or the per-set
// overflow list (scanned unconditionally) -> exact; min over a fixed
// multiset is order-independent -> deterministic under graph replay.
// Direct dx*dx+dy*dy (no cancellation) -> absmax ~1e-6. No atomics on
// output; each query thread writes its own result.

#define G     64
#define GG    (G * G)
#define CAP   64
#define OCAP  4096          // can hold an entire set -> points never dropped
#define CELLW 0.15625f      // 10/64
#define INVW  6.4f          // 64/10
#define NSETS 32            // 2 sets * B

// ---------- zero counters ----------
__global__ __launch_bounds__(256) void grid_zero(unsigned int* __restrict__ cnts, int n) {
    int i = blockIdx.x * 256 + threadIdx.x;
    if (i < n) cnts[i] = 0u;
}

// ---------- build buckets ----------
__global__ __launch_bounds__(256) void grid_build(
    const float2* __restrict__ tpts, const float2* __restrict__ apts,
    unsigned int* __restrict__ counts,   // [NSETS][GG]
    unsigned int* __restrict__ ovfcnt,   // [NSETS]
    float2* __restrict__ buckets,        // [NSETS][GG][CAP]
    float2* __restrict__ ovf,            // [NSETS][OCAP]
    int M, int N, int B)
{
    int idx = blockIdx.x * 256 + threadIdx.x;
    int total = B * (M + N);
    if (idx >= total) return;

    int s; float2 p;
    if (idx < B * M) { s = idx / M;             p = tpts[idx]; }          // target -> set b
    else             { int j = idx - B * M; s = B + j / N; p = apts[j]; } // actual -> set B+b

    int cx = (int)floorf((p.x + 5.0f) * INVW);
    int cy = (int)floorf((p.y + 5.0f) * INVW);
    cx = cx < 0 ? 0 : (cx > G - 1 ? G - 1 : cx);
    cy = cy < 0 ? 0 : (cy > G - 1 ? G - 1 : cy);
    int c = s * GG + cy * G + cx;

    unsigned slot = atomicAdd(&counts[c], 1u);
    if (slot < CAP) {
        buckets[(size_t)c * CAP + slot] = p;
    } else {
        unsigned o = atomicAdd(&ovfcnt[s], 1u);
        if (o < OCAP) ovf[(size_t)s * OCAP + o] = p;   // OCAP=set size: never full
    }
}

// ---------- query: ring search, one thread per query ----------
__global__ __launch_bounds__(256) void grid_query(
    const float2* __restrict__ tpts, const float2* __restrict__ apts,
    const unsigned int* __restrict__ counts,
    const unsigned int* __restrict__ ovfcnt,
    const float2* __restrict__ buckets,
    const float2* __restrict__ ovf,
    float* __restrict__ out, int M, int N, int B)
{
    int tq = blockIdx.x * 256 + threadIdx.x;
    int total = B * (M + N);
    if (tq >= total) return;

    int rs; float2 q; size_t oidx;
    if (tq < B * M) {                 // forward: query=target, refs=actual
        int b = tq / M;
        q = tpts[tq];
        rs = B + b;
        oidx = (size_t)tq;
    } else {                          // backward: query=actual, refs=target
        int j = tq - B * M;
        int b = j / N;
        q = apts[j];
        rs = b;
        oidx = (size_t)B * M + j;
    }

    float qx = q.x, qy = q.y;
    int cx = (int)floorf((qx + 5.0f) * INVW);
    int cy = (int)floorf((qy + 5.0f) * INVW);
    cx = cx < 0 ? 0 : (cx > G - 1 ? G - 1 : cx);
    cy = cy < 0 ? 0 : (cy > G - 1 ? G - 1 : cy);

    const unsigned int* __restrict__ scnt = counts + (size_t)rs * GG;
    const float2* __restrict__ sbkt = buckets + (size_t)rs * GG * CAP;

    float best = 3.0e38f;

    for (int r = 0; r <= G; ++r) {
        for (int dy = -r; dy <= r; ++dy) {
            int yy = cy + dy;
            if ((unsigned)yy >= (unsigned)G) continue;
            int rowb = yy * G;
            int x0, x1, step;
            if (dy == -r || dy == r) { x0 = cx - r; x1 = cx + r; step = 1; }
            else                     { x0 = cx - r; x1 = cx + r; step = 2 * r; }
            if (x0 < 0) x0 = (step == 1) ? 0 : x1;       // keep only in-range edges
            for (int xx = x0; xx <= x1; xx += step) {
                if ((unsigned)xx >= (unsigned)G) continue;
                int c = rowb + xx;
                unsigned cnt = scnt[c];
                if (cnt > CAP) cnt = CAP;
                const float2* __restrict__ bp = sbkt + (size_t)c * CAP;
                for (unsigned j = 0; j < cnt; ++j) {
                    float2 p = bp[j];
                    float dx = qx - p.x, dyf = qy - p.y;
                    best = fminf(best, fmaf(dx, dx, dyf * dyf));
                }
            }
        }
        float bound = (float)r * CELLW;
        if (best <= bound * bound) break;
    }

    // overflow list (usually empty; makes exactness unconditional)
    unsigned oc = ovfcnt[rs];
    if (oc > OCAP) oc = OCAP;
    const float2* __restrict__ op = ovf + (size_t)rs * OCAP;
    for (unsigned j = 0; j < oc; ++j) {
        float2 p = op[j];
        float dx = qx - p.x, dyf = qy - p.y;
        best = fminf(best, fmaf(dx, dx, dyf * dyf));
    }

    out[oidx] = sqrtf(best);
}

// ---------------- fallback (round-5 proven brute force) ----------------
#define BLK 256
#define TM  8
#define RC  32

__device__ __forceinline__ float min3f(float a, float b, float c) {
    float d;
    asm("v_min3_f32 %0, %1, %2, %3" : "=v"(d) : "v"(a), "v"(b), "v"(c));
    return d;
}

__global__ __launch_bounds__(256) void chamfer_init(unsigned int* __restrict__ out, int n) {
    int i = blockIdx.x * 256 + threadIdx.x;
    if (i < n) out[i] = 0x7F800000u;
}

__global__ __launch_bounds__(BLK) void chamfer_partial(
    const float2* __restrict__ tpts, const float2* __restrict__ apts,
    unsigned int* __restrict__ out, int M, int N, int B)
{
    const int b = blockIdx.y, zc = blockIdx.z;
    const int dir = zc & 1, rc = zc >> 1;
    const float2* __restrict__ Q = dir ? apts : tpts;
    const float2* __restrict__ R = dir ? tpts : apts;
    const int NQ = dir ? N : M, NR = dir ? M : N;
    unsigned int* __restrict__ o =
        out + (dir ? ((size_t)B * M + (size_t)b * N) : ((size_t)b * M));
    const float2* __restrict__ q = Q + (size_t)b * NQ;
    const float2* __restrict__ r = R + (size_t)b * NR;
    const int clen = (NR + RC - 1) / RC;
    const int rbeg = rc * clen;
    const int rend = (rbeg + clen < NR) ? (rbeg + clen) : NR;
    if (rbeg >= rend) return;
    int qi[TM]; float n2x[TM], n2y[TM], qn[TM], mn[TM];
#pragma unroll
    for (int k = 0; k < TM; ++k) {
        qi[k] = blockIdx.x * (BLK * TM) + k * BLK + (int)threadIdx.x;
        int idx = qi[k] < NQ ? qi[k] : NQ - 1;
        float2 p = q[idx];
        n2x[k] = -2.0f * p.x; n2y[k] = -2.0f * p.y;
        qn[k] = fmaf(p.y, p.y, p.x * p.x); mn[k] = 3.0e38f;
    }
    int n = rbeg;
    for (; n + 8 <= rend; n += 8) {
        float vx[8], vy[8], va[8];
#pragma unroll
        for (int g = 0; g < 4; ++g) {
            float4 p4 = *(const float4*)&r[n + 2 * g];
            vx[2*g] = p4.x; vy[2*g] = p4.y; vx[2*g+1] = p4.z; vy[2*g+1] = p4.w;
            va[2*g]   = fmaf(p4.y, p4.y, p4.x * p4.x);
            va[2*g+1] = fmaf(p4.w, p4.w, p4.z * p4.z);
        }
#pragma unroll
        for (int k = 0; k < TM; ++k) {
            float v[8];
#pragma unroll
            for (int j = 0; j < 8; ++j)
                v[j] = fmaf(n2x[k], vx[j], fmaf(n2y[k], vy[j], va[j]));
            float m = min3f(v[0], v[1], v[2]);
            m = min3f(m, v[3], v[4]);
            m = min3f(m, v[5], v[6]);
            mn[k] = min3f(m, v[7], mn[k]);
        }
    }
    for (; n < rend; ++n) {
        float2 p = r[n];
        float va = fmaf(p.y, p.y, p.x * p.x);
#pragma unroll
        for (int k = 0; k < TM; ++k)
            mn[k] = fminf(mn[k], fmaf(n2x[k], p.x, fmaf(n2y[k], p.y, va)));
    }
#pragma unroll
    for (int k = 0; k < TM; ++k)
        if (qi[k] < NQ)
            atomicMin(&o[qi[k]], __float_as_uint(fmaxf(mn[k] + qn[k], 0.0f)));
}

__global__ __launch_bounds__(256) void chamfer_sqrt(unsigned int* __restrict__ io, int n) {
    int i = blockIdx.x * 256 + threadIdx.x;
    if (i < n) ((float*)io)[i] = sqrtf(__uint_as_float(io[i]));
}

// ---------------- launch ----------------
extern "C" void kernel_launch(void* const* d_in, const int* in_sizes, int n_in,
                              void* d_out, int out_size, void* d_ws, size_t ws_size,
                              hipStream_t stream) {
    const float2* tpts = (const float2*)d_in[0];
    const float2* apts = (const float2*)d_in[1];

    const int B = 16;
    const int M = in_sizes[0] / (B * 2);
    const int N = in_sizes[1] / (B * 2);
    const int total = B * (M + N);

    // ws layout
    size_t cnt_elems = (size_t)NSETS * GG + NSETS;
    size_t cnt_bytes = cnt_elems * sizeof(unsigned int);           // 524,416
    size_t bkt_bytes = (size_t)NSETS * GG * CAP * sizeof(float2);  // 67 MB
    size_t ovf_bytes = (size_t)NSETS * OCAP * sizeof(float2);      // 1 MB
    size_t need = cnt_bytes + bkt_bytes + ovf_bytes;

    if (ws_size >= need && M <= OCAP && N <= OCAP) {
        unsigned int* counts = (unsigned int*)d_ws;
        unsigned int* ovfcnt = counts + (size_t)NSETS * GG;
        float2* buckets = (float2*)((char*)d_ws + cnt_bytes);
        float2* ovf = buckets + (size_t)NSETS * GG * CAP;

        grid_zero<<<((int)cnt_elems + 255) / 256, 256, 0, stream>>>(counts, (int)cnt_elems);
        grid_build<<<(total + 255) / 256, 256, 0, stream>>>(
            tpts, apts, counts, ovfcnt, buckets, ovf, M, N, B);
        grid_query<<<(total + 255) / 256, 256, 0, stream>>>(
            tpts, apts, counts, ovfcnt, buckets, ovf, (float*)d_out, M, N, B);
    } else {
        unsigned int* out = (unsigned int*)d_out;
        chamfer_init<<<(total + 255) / 256, 256, 0, stream>>>(out, total);
        const int S = M > N ? M : N;
        dim3 grid((S + BLK * TM - 1) / (BLK * TM), B, 2 * RC);
        chamfer_partial<<<grid, dim3(BLK), 0, stream>>>(tpts, apts, out, M, N, B);
        chamfer_sqrt<<<(total + 255) / 256, 256, 0, stream>>>(out, total);
    }
}

// Round 10
// 70.714 us; speedup vs baseline: 2.0315x; 2.0315x over previous
//
#include <hip/hip_runtime.h>
#include <math.h>

// ChamferLoss: target [B,M,2] f32, actual [B,N,2] f32
// out = concat(forward[B,M], backward[B,N]) f32
//
// Round 10: grid NN with CSR + spatially-sorted queries.
// Round 9 failed on latency (VALUBusy 8%): 67MB CAP-padded buckets ->
// sparse HBM gathers; random-order queries -> no cache reuse, ring
// divergence. Fix: per-set CSR (sorted-by-cell point list, ~32KB/set =
// fits L1), queries processed in sorted order (lanes share cells/rings),
// row-segments of cells are contiguous CSR ranges.
// Exactness: ring stop when best^2 <= (r*CELLW)^2 — box projection is
// 1-Lipschitz so the bound holds for clamped points too (round 9 absmax=0).
// Determinism: scatter order within a cell is atomic-order-dependent, but
// min over the full multiset is order-independent -> identical output.

#define G     64
#define GG    (G * G)
#define CELLW 0.15625f      // 10/64
#define INVW  6.4f          // 64/10
#define NSETS 32            // 2 clouds * B

__device__ __forceinline__ int cell_of(float v) {
    int c = (int)floorf((v + 5.0f) * INVW);
    return c < 0 ? 0 : (c > G - 1 ? G - 1 : c);
}

// ---------- zero counts + cursors ----------
__global__ __launch_bounds__(256) void grid_zero(unsigned int* __restrict__ p, int n) {
    int i = blockIdx.x * 256 + threadIdx.x;
    if (i < n) p[i] = 0u;
}

// ---------- pass 1: count ----------
__global__ __launch_bounds__(256) void grid_count(
    const float2* __restrict__ tpts, const float2* __restrict__ apts,
    unsigned int* __restrict__ counts,   // [NSETS][GG]
    int M, int N, int B)
{
    int idx = blockIdx.x * 256 + threadIdx.x;
    int total = B * (M + N);
    if (idx >= total) return;
    int s; float2 p;
    if (idx < B * M) { s = idx / M; p = tpts[idx]; }
    else { int j = idx - B * M; s = B + j / N; p = apts[j]; }
    int c = s * GG + cell_of(p.y) * G + cell_of(p.x);
    atomicAdd(&counts[c], 1u);
}

// ---------- pass 2: per-set exclusive scan (one block per set) ----------
__global__ __launch_bounds__(256) void grid_scan(
    const unsigned int* __restrict__ counts,  // [NSETS][GG]
    unsigned int* __restrict__ starts)        // [NSETS][GG+1]
{
    __shared__ unsigned int ls[256];
    int s = blockIdx.x;
    int tid = threadIdx.x;
    unsigned int tmp[16], sum = 0;
    int base = s * GG + tid * 16;
#pragma unroll
    for (int k = 0; k < 16; ++k) { tmp[k] = counts[base + k]; sum += tmp[k]; }
    ls[tid] = sum;
    __syncthreads();
    for (int off = 1; off < 256; off <<= 1) {
        unsigned int v = (tid >= off) ? ls[tid - off] : 0u;
        __syncthreads();
        ls[tid] += v;
        __syncthreads();
    }
    unsigned int run = ls[tid] - sum;   // exclusive prefix of this thread's chunk
    int obase = s * (GG + 1) + tid * 16;
#pragma unroll
    for (int k = 0; k < 16; ++k) { starts[obase + k] = run; run += tmp[k]; }
    if (tid == 255) starts[s * (GG + 1) + GG] = run;
}

// ---------- pass 3: scatter points sorted by cell ----------
__global__ __launch_bounds__(256) void grid_scatter(
    const float2* __restrict__ tpts, const float2* __restrict__ apts,
    const unsigned int* __restrict__ starts,  // [NSETS][GG+1]
    unsigned int* __restrict__ cursor,        // [NSETS][GG] (zeroed)
    float2* __restrict__ spts,                // [NSETS][S]
    unsigned int* __restrict__ sidx,          // [NSETS][S] -> out index
    int M, int N, int B, int S)
{
    int idx = blockIdx.x * 256 + threadIdx.x;
    int total = B * (M + N);
    if (idx >= total) return;
    int s; float2 p; unsigned int oid;
    if (idx < B * M) { s = idx / M; p = tpts[idx]; oid = (unsigned)idx; }
    else {
        int j = idx - B * M; s = B + j / N; p = apts[j];
        oid = (unsigned)(B * M + j);
    }
    int lc = cell_of(p.y) * G + cell_of(p.x);
    unsigned int pos = starts[s * (GG + 1) + lc] + atomicAdd(&cursor[s * GG + lc], 1u);
    spts[(size_t)s * S + pos] = p;
    sidx[(size_t)s * S + pos] = oid;
}

// ---------- pass 4: query (sorted order; one block per set slice) ----------
__global__ __launch_bounds__(256) void grid_query(
    const unsigned int* __restrict__ starts,
    const float2* __restrict__ spts,
    const unsigned int* __restrict__ sidx,
    float* __restrict__ out, int M, int N, int B, int S)
{
    int s = blockIdx.y;
    int cnt = (s < B) ? M : N;
    int i = blockIdx.x * 256 + threadIdx.x;
    if (i >= cnt) return;

    float2 q = spts[(size_t)s * S + i];
    unsigned int oid = sidx[(size_t)s * S + i];
    int rs = (s < B) ? (B + s) : (s - B);

    const unsigned int* __restrict__ st = starts + (size_t)rs * (GG + 1);
    const float2* __restrict__ rp = spts + (size_t)rs * S;

    float qx = q.x, qy = q.y;
    int cx = cell_of(qx), cy = cell_of(qy);

    float best = 3.0e38f;

    for (int r = 0; r <= G; ++r) {
        if (r == 0) {
            int c = cy * G + cx;
            unsigned int j0 = st[c], j1 = st[c + 1];
            for (unsigned int j = j0; j < j1; ++j) {
                float2 p = rp[j];
                float dx = qx - p.x, dy = qy - p.y;
                best = fminf(best, fmaf(dx, dx, dy * dy));
            }
        } else {
            int x0 = cx - r; if (x0 < 0) x0 = 0;
            int x1 = cx + r; if (x1 > G - 1) x1 = G - 1;
            // top & bottom rows: contiguous CSR range over [x0..x1]
#pragma unroll
            for (int e = 0; e < 2; ++e) {
                int yy = e ? cy + r : cy - r;
                if ((unsigned)yy < (unsigned)G) {
                    int rowb = yy * G;
                    unsigned int j0 = st[rowb + x0], j1 = st[rowb + x1 + 1];
                    for (unsigned int j = j0; j < j1; ++j) {
                        float2 p = rp[j];
                        float dx = qx - p.x, dy = qy - p.y;
                        best = fminf(best, fmaf(dx, dx, dy * dy));
                    }
                }
            }
            // middle rows: left & right edge cells only
            for (int dy = -(r - 1); dy <= r - 1; ++dy) {
                int yy = cy + dy;
                if ((unsigned)yy >= (unsigned)G) continue;
                int rowb = yy * G;
#pragma unroll
                for (int e = 0; e < 2; ++e) {
                    int xx = e ? cx + r : cx - r;
                    if ((unsigned)xx >= (unsigned)G) continue;
                    int c = rowb + xx;
                    unsigned int j0 = st[c], j1 = st[c + 1];
                    for (unsigned int j = j0; j < j1; ++j) {
                        float2 p = rp[j];
                        float dxf = qx - p.x, dyf = qy - p.y;
                        best = fminf(best, fmaf(dxf, dxf, dyf * dyf));
                    }
                }
            }
        }
        float bound = (float)r * CELLW;
        if (best <= bound * bound) break;
    }

    out[oid] = sqrtf(best);
}

// ---------------- fallback (round-5 proven brute force) ----------------
#define BLK 256
#define TM  8
#define RC  32

__device__ __forceinline__ float min3f(float a, float b, float c) {
    float d;
    asm("v_min3_f32 %0, %1, %2, %3" : "=v"(d) : "v"(a), "v"(b), "v"(c));
    return d;
}

__global__ __launch_bounds__(256) void chamfer_init(unsigned int* __restrict__ out, int n) {
    int i = blockIdx.x * 256 + threadIdx.x;
    if (i < n) out[i] = 0x7F800000u;
}

__global__ __launch_bounds__(BLK) void chamfer_partial(
    const float2* __restrict__ tpts, const float2* __restrict__ apts,
    unsigned int* __restrict__ out, int M, int N, int B)
{
    const int b = blockIdx.y, zc = blockIdx.z;
    const int dir = zc & 1, rc = zc >> 1;
    const float2* __restrict__ Q = dir ? apts : tpts;
    const float2* __restrict__ R = dir ? tpts : apts;
    const int NQ = dir ? N : M, NR = dir ? M : N;
    unsigned int* __restrict__ o =
        out + (dir ? ((size_t)B * M + (size_t)b * N) : ((size_t)b * M));
    const float2* __restrict__ q = Q + (size_t)b * NQ;
    const float2* __restrict__ r = R + (size_t)b * NR;
    const int clen = (NR + RC - 1) / RC;
    const int rbeg = rc * clen;
    const int rend = (rbeg + clen < NR) ? (rbeg + clen) : NR;
    if (rbeg >= rend) return;
    int qi[TM]; float n2x[TM], n2y[TM], qn[TM], mn[TM];
#pragma unroll
    for (int k = 0; k < TM; ++k) {
        qi[k] = blockIdx.x * (BLK * TM) + k * BLK + (int)threadIdx.x;
        int idx = qi[k] < NQ ? qi[k] : NQ - 1;
        float2 p = q[idx];
        n2x[k] = -2.0f * p.x; n2y[k] = -2.0f * p.y;
        qn[k] = fmaf(p.y, p.y, p.x * p.x); mn[k] = 3.0e38f;
    }
    int n = rbeg;
    for (; n + 8 <= rend; n += 8) {
        float vx[8], vy[8], va[8];
#pragma unroll
        for (int g = 0; g < 4; ++g) {
            float4 p4 = *(const float4*)&r[n + 2 * g];
            vx[2*g] = p4.x; vy[2*g] = p4.y; vx[2*g+1] = p4.z; vy[2*g+1] = p4.w;
            va[2*g]   = fmaf(p4.y, p4.y, p4.x * p4.x);
            va[2*g+1] = fmaf(p4.w, p4.w, p4.z * p4.z);
        }
#pragma unroll
        for (int k = 0; k < TM; ++k) {
            float v[8];
#pragma unroll
            for (int j = 0; j < 8; ++j)
                v[j] = fmaf(n2x[k], vx[j], fmaf(n2y[k], vy[j], va[j]));
            float m = min3f(v[0], v[1], v[2]);
            m = min3f(m, v[3], v[4]);
            m = min3f(m, v[5], v[6]);
            mn[k] = min3f(m, v[7], mn[k]);
        }
    }
    for (; n < rend; ++n) {
        float2 p = r[n];
        float va = fmaf(p.y, p.y, p.x * p.x);
#pragma unroll
        for (int k = 0; k < TM; ++k)
            mn[k] = fminf(mn[k], fmaf(n2x[k], p.x, fmaf(n2y[k], p.y, va)));
    }
#pragma unroll
    for (int k = 0; k < TM; ++k)
        if (qi[k] < NQ)
            atomicMin(&o[qi[k]], __float_as_uint(fmaxf(mn[k] + qn[k], 0.0f)));
}

__global__ __launch_bounds__(256) void chamfer_sqrt(unsigned int* __restrict__ io, int n) {
    int i = blockIdx.x * 256 + threadIdx.x;
    if (i < n) ((float*)io)[i] = sqrtf(__uint_as_float(io[i]));
}

// ---------------- launch ----------------
extern "C" void kernel_launch(void* const* d_in, const int* in_sizes, int n_in,
                              void* d_out, int out_size, void* d_ws, size_t ws_size,
                              hipStream_t stream) {
    const float2* tpts = (const float2*)d_in[0];
    const float2* apts = (const float2*)d_in[1];

    const int B = 16;
    const int M = in_sizes[0] / (B * 2);
    const int N = in_sizes[1] / (B * 2);
    const int S = M > N ? M : N;
    const int total = B * (M + N);

    // ws layout: counts | cursor | starts | spts | sidx
    size_t counts_e = (size_t)NSETS * GG;
    size_t starts_e = (size_t)NSETS * (GG + 1);
    size_t counts_b = counts_e * 4, cursor_b = counts_e * 4, starts_b = starts_e * 4;
    size_t spts_b = (size_t)NSETS * S * sizeof(float2);
    size_t sidx_b = (size_t)NSETS * S * 4;
    size_t need = counts_b + cursor_b + starts_b + spts_b + sidx_b;

    if (ws_size >= need) {
        unsigned int* counts = (unsigned int*)d_ws;
        unsigned int* cursor = counts + counts_e;
        unsigned int* starts = cursor + counts_e;
        float2* spts = (float2*)((char*)d_ws + counts_b + cursor_b + starts_b);
        unsigned int* sidx = (unsigned int*)((char*)spts + spts_b);

        int zn = (int)(counts_e * 2);
        grid_zero<<<(zn + 255) / 256, 256, 0, stream>>>(counts, zn);
        grid_count<<<(total + 255) / 256, 256, 0, stream>>>(tpts, apts, counts, M, N, B);
        grid_scan<<<NSETS, 256, 0, stream>>>(counts, starts);
        grid_scatter<<<(total + 255) / 256, 256, 0, stream>>>(
            tpts, apts, starts, cursor, spts, sidx, M, N, B, S);
        dim3 qgrid((S + 255) / 256, NSETS);
        grid_query<<<qgrid, 256, 0, stream>>>(starts, spts, sidx,
                                              (float*)d_out, M, N, B, S);
    } else {
        unsigned int* out = (unsigned int*)d_out;
        chamfer_init<<<(total + 255) / 256, 256, 0, stream>>>(out, total);
        dim3 grid((S + BLK * TM - 1) / (BLK * TM), B, 2 * RC);
        chamfer_partial<<<grid, dim3(BLK), 0, stream>>>(tpts, apts, out, M, N, B);
        chamfer_sqrt<<<(total + 255) / 256, 256, 0, stream>>>(out, total);
    }
}

// Round 11
// 58.665 us; speedup vs baseline: 2.4488x; 1.2054x over previous
//
#include <hip/hip_runtime.h>
#include <math.h>

// ChamferLoss: target [B,M,2] f32, actual [B,N,2] f32
// out = concat(forward[B,M], backward[B,N]) f32
//
// Round 11: grid NN, CSR + sorted queries (round 10) with two fixes:
//  - 4 lanes per query (LG=4): serial candidate chain / 4, wave count x 4
//    (-> 32 waves/CU), per-ring 2-step shfl_xor min consensus (exact).
//  - fused build: one block per set does LDS histogram -> LDS scan ->
//    scatter (replaces 4 kernels + global atomics).
// Exactness: ring stop when best^2 <= (r*CELLW)^2 (box projection is
// 1-Lipschitz; empirically absmax=0.0 in rounds 9/10). Determinism:
// within-cell scatter order varies, but each query minimizes over the
// full multiset -> order-independent; every ws slot rewritten each call.

#define G     64
#define GG    (G * G)
#define CELLW 0.15625f      // 10/64
#define INVW  6.4f          // 64/10
#define NSETS 32            // 2 clouds * B
#define LG    4             // lanes per query

__device__ __forceinline__ int cell_of(float v) {
    int c = (int)floorf((v + 5.0f) * INVW);
    return c < 0 ? 0 : (c > G - 1 ? G - 1 : c);
}

// ---------- fused build: one block per set ----------
__global__ __launch_bounds__(256) void grid_build(
    const float2* __restrict__ tpts, const float2* __restrict__ apts,
    unsigned int* __restrict__ gstarts,  // [NSETS][GG+1]
    float2* __restrict__ spts,           // [NSETS][S]
    unsigned int* __restrict__ sidx,     // [NSETS][S]
    int M, int N, int B, int S)
{
    __shared__ unsigned int hist[GG];
    __shared__ unsigned int cur[GG];
    __shared__ unsigned int part[256];

    const int s = blockIdx.x;
    const int tid = threadIdx.x;
    const int cnt = (s < B) ? M : N;
    const float2* __restrict__ pts =
        (s < B) ? (tpts + (size_t)s * M) : (apts + (size_t)(s - B) * N);
    const unsigned int obase =
        (s < B) ? (unsigned)(s * M) : (unsigned)(B * M + (s - B) * N);

    for (int i = tid; i < GG; i += 256) hist[i] = 0u;
    __syncthreads();

    for (int i = tid; i < cnt; i += 256) {
        float2 p = pts[i];
        atomicAdd(&hist[cell_of(p.y) * G + cell_of(p.x)], 1u);
    }
    __syncthreads();

    // scan: each thread owns 16 consecutive cells
    unsigned int tmp[16], sum = 0;
    int base = tid * 16;
#pragma unroll
    for (int k = 0; k < 16; ++k) { tmp[k] = hist[base + k]; sum += tmp[k]; }
    part[tid] = sum;
    __syncthreads();
    for (int off = 1; off < 256; off <<= 1) {
        unsigned int v = (tid >= off) ? part[tid - off] : 0u;
        __syncthreads();
        part[tid] += v;
        __syncthreads();
    }
    unsigned int run = part[tid] - sum;   // exclusive prefix
    unsigned int* __restrict__ gs = gstarts + (size_t)s * (GG + 1);
#pragma unroll
    for (int k = 0; k < 16; ++k) {
        cur[base + k] = run;
        gs[base + k] = run;
        run += tmp[k];
    }
    if (tid == 255) gs[GG] = run;
    __syncthreads();

    // scatter sorted-by-cell
    for (int i = tid; i < cnt; i += 256) {
        float2 p = pts[i];
        int c = cell_of(p.y) * G + cell_of(p.x);
        unsigned int pos = atomicAdd(&cur[c], 1u);
        spts[(size_t)s * S + pos] = p;
        sidx[(size_t)s * S + pos] = obase + (unsigned)i;
    }
}

// ---------- query: LG lanes per query, ring search over CSR ----------
__global__ __launch_bounds__(256) void grid_query(
    const unsigned int* __restrict__ starts,
    const float2* __restrict__ spts,
    const unsigned int* __restrict__ sidx,
    float* __restrict__ out, int M, int N, int B, int S)
{
    const int s = blockIdx.y;
    const int cnt = (s < B) ? M : N;
    const int qpb = 256 / LG;
    const int i = blockIdx.x * qpb + ((int)threadIdx.x / LG);
    const int sub = (int)threadIdx.x & (LG - 1);
    if (i >= cnt) return;

    float2 q = spts[(size_t)s * S + i];
    unsigned int oid = sidx[(size_t)s * S + i];
    const int rs = (s < B) ? (B + s) : (s - B);

    const unsigned int* __restrict__ st = starts + (size_t)rs * (GG + 1);
    const float2* __restrict__ rp = spts + (size_t)rs * S;

    const float qx = q.x, qy = q.y;
    const int cx = cell_of(qx), cy = cell_of(qy);

    float best = 3.0e38f;

    for (int r = 0; r <= G; ++r) {
        if (r == 0) {
            int c = cy * G + cx;
            unsigned int j0 = st[c], j1 = st[c + 1];
            for (unsigned int j = j0 + sub; j < j1; j += LG) {
                float2 p = rp[j];
                float dx = qx - p.x, dy = qy - p.y;
                best = fminf(best, fmaf(dx, dx, dy * dy));
            }
        } else {
            int x0 = cx - r; if (x0 < 0) x0 = 0;
            int x1 = cx + r; if (x1 > G - 1) x1 = G - 1;
            // top & bottom rows: one contiguous CSR range each
#pragma unroll
            for (int e = 0; e < 2; ++e) {
                int yy = e ? cy + r : cy - r;
                if ((unsigned)yy < (unsigned)G) {
                    int rowb = yy * G;
                    unsigned int j0 = st[rowb + x0], j1 = st[rowb + x1 + 1];
                    for (unsigned int j = j0 + sub; j < j1; j += LG) {
                        float2 p = rp[j];
                        float dx = qx - p.x, dy = qy - p.y;
                        best = fminf(best, fmaf(dx, dx, dy * dy));
                    }
                }
            }
            // middle rows: left/right edge cells
            for (int dy = -(r - 1); dy <= r - 1; ++dy) {
                int yy = cy + dy;
                if ((unsigned)yy >= (unsigned)G) continue;
                int rowb = yy * G;
#pragma unroll
                for (int e = 0; e < 2; ++e) {
                    int xx = e ? cx + r : cx - r;
                    if ((unsigned)xx >= (unsigned)G) continue;
                    int c = rowb + xx;
                    unsigned int j0 = st[c], j1 = st[c + 1];
                    for (unsigned int j = j0 + sub; j < j1; j += LG) {
                        float2 p = rp[j];
                        float dxf = qx - p.x, dyf = qy - p.y;
                        best = fminf(best, fmaf(dxf, dxf, dyf * dyf));
                    }
                }
            }
        }
        // group consensus (lanes 4q..4q+3): reduced best on all 4 lanes
        best = fminf(best, __shfl_xor(best, 1, 64));
        best = fminf(best, __shfl_xor(best, 2, 64));
        float bound = (float)r * CELLW;
        if (best <= bound * bound) break;
    }

    if (sub == 0) out[oid] = sqrtf(best);
}

// ---------------- fallback (round-5 proven brute force) ----------------
#define BLK 256
#define TM  8
#define RC  32

__device__ __forceinline__ float min3f(float a, float b, float c) {
    float d;
    asm("v_min3_f32 %0, %1, %2, %3" : "=v"(d) : "v"(a), "v"(b), "v"(c));
    return d;
}

__global__ __launch_bounds__(256) void chamfer_init(unsigned int* __restrict__ out, int n) {
    int i = blockIdx.x * 256 + threadIdx.x;
    if (i < n) out[i] = 0x7F800000u;
}

__global__ __launch_bounds__(BLK) void chamfer_partial(
    const float2* __restrict__ tpts, const float2* __restrict__ apts,
    unsigned int* __restrict__ out, int M, int N, int B)
{
    const int b = blockIdx.y, zc = blockIdx.z;
    const int dir = zc & 1, rc = zc >> 1;
    const float2* __restrict__ Q = dir ? apts : tpts;
    const float2* __restrict__ R = dir ? tpts : apts;
    const int NQ = dir ? N : M, NR = dir ? M : N;
    unsigned int* __restrict__ o =
        out + (dir ? ((size_t)B * M + (size_t)b * N) : ((size_t)b * M));
    const float2* __restrict__ q = Q + (size_t)b * NQ;
    const float2* __restrict__ r = R + (size_t)b * NR;
    const int clen = (NR + RC - 1) / RC;
    const int rbeg = rc * clen;
    const int rend = (rbeg + clen < NR) ? (rbeg + clen) : NR;
    if (rbeg >= rend) return;
    int qi[TM]; float n2x[TM], n2y[TM], qn[TM], mn[TM];
#pragma unroll
    for (int k = 0; k < TM; ++k) {
        qi[k] = blockIdx.x * (BLK * TM) + k * BLK + (int)threadIdx.x;
        int idx = qi[k] < NQ ? qi[k] : NQ - 1;
        float2 p = q[idx];
        n2x[k] = -2.0f * p.x; n2y[k] = -2.0f * p.y;
        qn[k] = fmaf(p.y, p.y, p.x * p.x); mn[k] = 3.0e38f;
    }
    int n = rbeg;
    for (; n + 8 <= rend; n += 8) {
        float vx[8], vy[8], va[8];
#pragma unroll
        for (int g = 0; g < 4; ++g) {
            float4 p4 = *(const float4*)&r[n + 2 * g];
            vx[2*g] = p4.x; vy[2*g] = p4.y; vx[2*g+1] = p4.z; vy[2*g+1] = p4.w;
            va[2*g]   = fmaf(p4.y, p4.y, p4.x * p4.x);
            va[2*g+1] = fmaf(p4.w, p4.w, p4.z * p4.z);
        }
#pragma unroll
        for (int k = 0; k < TM; ++k) {
            float v[8];
#pragma unroll
            for (int j = 0; j < 8; ++j)
                v[j] = fmaf(n2x[k], vx[j], fmaf(n2y[k], vy[j], va[j]));
            float m = min3f(v[0], v[1], v[2]);
            m = min3f(m, v[3], v[4]);
            m = min3f(m, v[5], v[6]);
            mn[k] = min3f(m, v[7], mn[k]);
        }
    }
    for (; n < rend; ++n) {
        float2 p = r[n];
        float va = fmaf(p.y, p.y, p.x * p.x);
#pragma unroll
        for (int k = 0; k < TM; ++k)
            mn[k] = fminf(mn[k], fmaf(n2x[k], p.x, fmaf(n2y[k], p.y, va)));
    }
#pragma unroll
    for (int k = 0; k < TM; ++k)
        if (qi[k] < NQ)
            atomicMin(&o[qi[k]], __float_as_uint(fmaxf(mn[k] + qn[k], 0.0f)));
}

__global__ __launch_bounds__(256) void chamfer_sqrt(unsigned int* __restrict__ io, int n) {
    int i = blockIdx.x * 256 + threadIdx.x;
    if (i < n) ((float*)io)[i] = sqrtf(__uint_as_float(io[i]));
}

// ---------------- launch ----------------
extern "C" void kernel_launch(void* const* d_in, const int* in_sizes, int n_in,
                              void* d_out, int out_size, void* d_ws, size_t ws_size,
                              hipStream_t stream) {
    const float2* tpts = (const float2*)d_in[0];
    const float2* apts = (const float2*)d_in[1];

    const int B = 16;
    const int M = in_sizes[0] / (B * 2);
    const int N = in_sizes[1] / (B * 2);
    const int S = M > N ? M : N;
    const int total = B * (M + N);

    // ws layout: starts | spts | sidx
    size_t starts_b = (size_t)NSETS * (GG + 1) * 4;
    size_t spts_b   = (size_t)NSETS * S * sizeof(float2);
    size_t sidx_b   = (size_t)NSETS * S * 4;
    size_t need = starts_b + spts_b + sidx_b;

    if (ws_size >= need) {
        unsigned int* starts = (unsigned int*)d_ws;
        float2* spts = (float2*)((char*)d_ws + starts_b);
        unsigned int* sidx = (unsigned int*)((char*)spts + spts_b);

        grid_build<<<NSETS, 256, 0, stream>>>(tpts, apts, starts, spts, sidx, M, N, B, S);
        const int qpb = 256 / LG;
        dim3 qgrid((S + qpb - 1) / qpb, NSETS);
        grid_query<<<qgrid, 256, 0, stream>>>(starts, spts, sidx,
                                              (float*)d_out, M, N, B, S);
    } else {
        unsigned int* out = (unsigned int*)d_out;
        chamfer_init<<<(total + 255) / 256, 256, 0, stream>>>(out, total);
        dim3 grid((S + BLK * TM - 1) / (BLK * TM), B, 2 * RC);
        chamfer_partial<<<grid, dim3(BLK), 0, stream>>>(tpts, apts, out, M, N, B);
        chamfer_sqrt<<<(total + 255) / 256, 256, 0, stream>>>(out, total);
    }
}